// Round 1
// baseline (209.554 us; speedup 1.0000x reference)
//
#include <hip/hip_runtime.h>

#define T_DATA 20000
#define S_NO   128
#define T_HIST 100
#define J_PAD  104              // conv taps padded to 13 chunks of 8 (zeros past 99)
#define NELEM  (T_DATA * S_NO)  // 2,560,000

__device__ __forceinline__ float sigm(float v) {
    return 1.0f / (1.0f + __expf(-v));
}

__device__ __forceinline__ void fma4(float4& a, float s, const float4 c) {
    a.x = fmaf(s, c.x, a.x); a.y = fmaf(s, c.y, a.y);
    a.z = fmaf(s, c.z, a.z); a.w = fmaf(s, c.w, a.w);
}

// ---------------------------------------------------------------------------
// K1: prep (17 blocks). blocks 0..15: transpose C -> Ct[k][s]
// block 16: ancestor kernel transposed [j][s] (padded to 104), history
// kernel [s][j], flag = any(K_hist != 0)
// ---------------------------------------------------------------------------
__global__ void __launch_bounds__(256) k1_prep(const float* __restrict__ C,
                        const float* __restrict__ K_spike,
                        const float* __restrict__ tau_spike,
                        const float* __restrict__ delta_spike,
                        const float* __restrict__ tau_hist,
                        const float* __restrict__ K_hist,
                        const float* __restrict__ delta_hist,
                        float* __restrict__ Ct,
                        float* __restrict__ anc_kT,
                        float* __restrict__ hist_k,
                        int* __restrict__ flag) {
    const int tid = threadIdx.x;
    const int b   = blockIdx.x;
    if (b < 16) {
#pragma unroll
        for (int i = 0; i < 4; ++i) {
            const int q = b * 1024 + i * 256 + tid;   // q = s*128 + k
            Ct[(q & 127) * S_NO + (q >> 7)] = C[q];
        }
        return;
    }
    const int s    = tid & 127;
    const int half = tid >> 7;
    {   // ancestor kernel transposed, padded: anc_kT[j*128 + s], j in [0,104)
        float d  = delta_spike[s];
        float i0 = __expf(-tau_spike[0]);
        float i1 = __expf(-tau_spike[1]);
        float i2 = __expf(-tau_spike[2]);
        float k0 = K_spike[s * 3 + 0], k1 = K_spike[s * 3 + 1], k2 = K_spike[s * 3 + 2];
        for (int j = half * 52; j < half * 52 + 52; ++j) {
            float v = 0.0f;
            if (j < T_HIST) {
                float t  = fmaxf((float)j - d, 0.0f);
                float x0 = t * i0, x1 = t * i1, x2 = t * i2;
                v = k0 * x0 * __expf(-x0) + k1 * x1 * __expf(-x1) + k2 * x2 * __expf(-x2);
            }
            anc_kT[j * S_NO + s] = v;
        }
    }
    {   // history kernel per-subunit: hist_k[s*100 + j]
        float d  = delta_hist[s];
        float i0 = __expf(-tau_hist[0]);
        float i1 = __expf(-tau_hist[1]);
        float i2 = __expf(-tau_hist[2]);
        float k0 = K_hist[s * 3 + 0], k1 = K_hist[s * 3 + 1], k2 = K_hist[s * 3 + 2];
        for (int j = half * 50; j < half * 50 + 50; ++j) {
            float t  = fmaxf((float)j - d, 0.0f);
            float x0 = t * i0, x1 = t * i1, x2 = t * i2;
            hist_k[s * T_HIST + j] =
                k0 * x0 * __expf(-x0) + k1 * x1 * __expf(-x1) + k2 * x2 * __expf(-x2);
        }
    }
    if (tid == 0) *flag = 0;
    __syncthreads();
    if (tid < 128) {
        if (K_hist[s * 3] != 0.0f || K_hist[s * 3 + 1] != 0.0f || K_hist[s * 3 + 2] != 0.0f)
            atomicOr(flag, 1);
    }
}

// ---------------------------------------------------------------------------
// K2: single GEMM  A = Z @ C^T (-> ws). R-GEMM moved into K3 (no halo needed),
// eliminating the R write + re-read round trip (20.5 MB HBM) and halving K2.
// Block 32t x 128s, thread 4t x 4s (known-good R3/R6 structure).
// ---------------------------------------------------------------------------
__global__ void __launch_bounds__(256) k2_gemm(const float* __restrict__ Z,
                                               const float* __restrict__ Ct,
                                               float* __restrict__ A) {
    __shared__ float Zt[32 * 128];
    const int t0  = blockIdx.x * 32;
    const int tid = threadIdx.x;
    {
        const float4* Zg = (const float4*)(Z + t0 * S_NO);
        float4* Zl = (float4*)Zt;
        for (int q = tid; q < 1024; q += 256) Zl[q] = Zg[q];
    }
    __syncthreads();
    const int sg = tid & 31;          // s0 = sg*4
    const int tg = tid >> 5;          // 0..7 -> local t = tg*4 + i
    const int s0 = sg * 4;
    float4 accA[4] = {{0,0,0,0},{0,0,0,0},{0,0,0,0},{0,0,0,0}};
    for (int k4 = 0; k4 < 32; ++k4) {
        const float4 c0 = *(const float4*)&Ct[(k4 * 4 + 0) * S_NO + s0];
        const float4 c1 = *(const float4*)&Ct[(k4 * 4 + 1) * S_NO + s0];
        const float4 c2 = *(const float4*)&Ct[(k4 * 4 + 2) * S_NO + s0];
        const float4 c3 = *(const float4*)&Ct[(k4 * 4 + 3) * S_NO + s0];
#pragma unroll
        for (int i = 0; i < 4; ++i) {
            const float4 z = *(const float4*)&Zt[(tg * 4 + i) * S_NO + k4 * 4];
            fma4(accA[i], z.x, c0); fma4(accA[i], z.y, c1);
            fma4(accA[i], z.z, c2); fma4(accA[i], z.w, c3);
        }
    }
#pragma unroll
    for (int i = 0; i < 4; ++i)
        *(float4*)&A[(t0 + tg * 4 + i) * S_NO + s0] = accA[i];
}

// ---------------------------------------------------------------------------
// K3: fused 100-tap conv + in-register R-GEMM (R = Y @ C^T) + final map.
// Gather-from-global conv, no LDS/barrier. Thread: one s, 8 t's.
// Conv: explicit double-buffered chunk pipeline (load chunk c+1 while
// FMA-ing chunk c). R-GEMM: Ct column is lane-coalesced + L2-hot; Y rows
// are wave-uniform float4 broadcasts (8 KB/block, L1-resident).
// ---------------------------------------------------------------------------
#define K3_LOGICAL 1250
#define K3_NPER    157                 // ceil(1250/8)
#define K3_PHYS    (8 * K3_NPER)       // 1256

__device__ __forceinline__ void k3_load_chunk(const float* __restrict__ A,
                                              const float* __restrict__ kT,
                                              int t0, int s, int c,
                                              float w[15], float kj[8]) {
    const int B = t0 - 8 * c - 8;
#pragma unroll
    for (int q = 0; q < 15; ++q) w[q] = A[(B + q) * S_NO + s];
#pragma unroll
    for (int r = 0; r < 8; ++r) kj[r] = kT[(8 * c + r) * S_NO + s];
}

__device__ __forceinline__ void k3_fma_chunk(const float w[15], const float kj[8],
                                             float acc[8]) {
#pragma unroll
    for (int r = 0; r < 8; ++r)
#pragma unroll
        for (int i = 0; i < 8; ++i)
            acc[i] = fmaf(kj[r], w[i + 7 - r], acc[i]);   // row = t0+i-1-(8c+r)
}

// guarded (t0 < 104) fallback: serial, with u>=0 checks — 7 blocks only
__device__ __forceinline__ void conv8_guard(const float* __restrict__ A,
                                            const float* __restrict__ kT,
                                            int t0, int s, float acc[8]) {
#pragma unroll 1
    for (int c = 0; c < 13; ++c) {
        const int B = t0 - 8 * c - 8;
        float w[15], kj[8];
#pragma unroll
        for (int q = 0; q < 15; ++q) {
            const int u = B + q;
            w[q] = (u >= 0) ? A[u * S_NO + s] : 0.0f;
        }
#pragma unroll
        for (int r = 0; r < 8; ++r) kj[r] = kT[(8 * c + r) * S_NO + s];
        k3_fma_chunk(w, kj, acc);
    }
}

__global__ void __launch_bounds__(256, 4) k3_fused(const float* __restrict__ A,
                                                const float* __restrict__ anc_kT,
                                                const float* __restrict__ Y,
                                                const float* __restrict__ Ct,
                                                const float* __restrict__ S_conv,
                                                const float* __restrict__ noise,
                                                const float* __restrict__ W_sub,
                                                const float* __restrict__ theta_syn,
                                                const float* __restrict__ theta_spike,
                                                const float* __restrict__ W_spike,
                                                const int* __restrict__ flag,
                                                float* __restrict__ out0,
                                                float* __restrict__ out1,
                                                float* __restrict__ out2,
                                                float* __restrict__ out3,
                                                float* __restrict__ Fws) {
    // bijective XCD swizzle over the padded grid [0, 1256)
    const int blk = (blockIdx.x & 7) * K3_NPER + (blockIdx.x >> 3);
    if (blk >= K3_LOGICAL) return;
    const int tid = threadIdx.x;
    const int s   = tid & 127;
    const int tg  = tid >> 7;                             // wave-uniform (0/1)
    const int t0  = blk * 16 + tg * 8;
    const int fl  = *flag;

    // prefetch the two HBM-cold final-map streams; latency hides under compute
    float sc[8], nz[8];
#pragma unroll
    for (int i = 0; i < 8; ++i) {
        const int n = (t0 + i) * S_NO + s;
        sc[i] = S_conv[n];
        nz[i] = noise[n];
    }

    // ---- in-register R-GEMM: accR[i] = sum_k Y[t0+i][k] * C[s][k] ----
    float accR[8] = {0,0,0,0,0,0,0,0};
    {
        const float* Yrow = Y + t0 * S_NO;
#pragma unroll 4
        for (int k4 = 0; k4 < 32; ++k4) {
            const float c0 = Ct[(k4 * 4 + 0) * S_NO + s];
            const float c1 = Ct[(k4 * 4 + 1) * S_NO + s];
            const float c2 = Ct[(k4 * 4 + 2) * S_NO + s];
            const float c3 = Ct[(k4 * 4 + 3) * S_NO + s];
#pragma unroll
            for (int i = 0; i < 8; ++i) {
                const float4 y = *(const float4*)&Yrow[i * S_NO + k4 * 4];
                accR[i] = fmaf(y.x, c0, accR[i]);
                accR[i] = fmaf(y.y, c1, accR[i]);
                accR[i] = fmaf(y.z, c2, accR[i]);
                accR[i] = fmaf(y.w, c3, accR[i]);
            }
        }
    }

    // ---- 100-tap ancestor conv on A ----
    float acc[8] = {0,0,0,0,0,0,0,0};
    if (t0 >= J_PAD) {
        // software-pipelined: double-buffered window/taps, rolled x2 loop
        float w0[15], k0[8], w1[15], k1[8];
        k3_load_chunk(A, anc_kT, t0, s, 0, w0, k0);
#pragma unroll 1
        for (int c = 0; c < 12; c += 2) {
            k3_load_chunk(A, anc_kT, t0, s, c + 1, w1, k1);
            k3_fma_chunk(w0, k0, acc);
            k3_load_chunk(A, anc_kT, t0, s, c + 2, w0, k0);
            k3_fma_chunk(w1, k1, acc);
        }
        k3_fma_chunk(w0, k0, acc);                        // chunk 12
    } else {
        conv8_guard(A, anc_kT, t0, s, acc);
    }

    if (fl == 0) {
        const float tsy = theta_syn[s], wsub = W_sub[s];
        const float wsp = W_spike[s],  tsp  = theta_spike[s];
#pragma unroll
        for (int i = 0; i < 8; ++i) {
            const int n = (t0 + i) * S_NO + s;
            const float x  = sigm(sc[i] + tsy + accR[i] + acc[i]);
            const float dn = fmaf(x, wsp, tsp);
            const float z  = sigm(dn + nz[i]);
            out0[n] = x * wsub;
            out1[n] = z;
            out2[n] = dn;
            out3[n] = dn;
        }
    } else {
        // Fws = filtered_ancest + raw_ancest (K4 consumes the sum)
#pragma unroll
        for (int i = 0; i < 8; ++i) Fws[(t0 + i) * S_NO + s] = acc[i] + accR[i];
    }
}

// ---------------------------------------------------------------------------
// K4: exact sequential recurrence (only when hist kernel != 0).
// Fws now already contains filtered + raw ancestor contribution.
// ---------------------------------------------------------------------------
__global__ void __launch_bounds__(64) k4_scan(const float* __restrict__ S_conv,
                                              const float* __restrict__ noise,
                                              const float* __restrict__ W_sub,
                                              const float* __restrict__ theta_syn,
                                              const float* __restrict__ theta_spike,
                                              const float* __restrict__ W_spike,
                                              const float* __restrict__ hist_k,
                                              const int* __restrict__ flag,
                                              const float* __restrict__ Fws,
                                              float* __restrict__ out0,
                                              float* __restrict__ out1,
                                              float* __restrict__ out2,
                                              float* __restrict__ out3) {
    if (*flag == 0) return;
    __shared__ float zr[128];
    const int s = blockIdx.x;
    const int l = threadIdx.x;
    zr[l] = 0.0f; zr[l + 64] = 0.0f;      // single wave: no barrier needed
    const float hk0 = (l < T_HIST) ? hist_k[s * T_HIST + l] : 0.0f;
    const float hk1 = (l + 64 < T_HIST) ? hist_k[s * T_HIST + l + 64] : 0.0f;
    const float tsy = theta_syn[s], wsub = W_sub[s];
    const float wsp = W_spike[s],  tsp  = theta_spike[s];
    for (int t = 0; t < T_DATA; ++t) {
        float fh = hk0 * zr[(t - 1 - l) & 127];
        fh = fmaf(hk1, zr[(t - 65 - l) & 127], fh);
#pragma unroll
        for (int m = 1; m < 64; m <<= 1) fh += __shfl_xor(fh, m, 64);
        const int n = t * S_NO + s;
        const float basev = S_conv[n] + tsy + Fws[n];
        const float x  = sigm(basev + fh);
        const float dn = fmaf(x, wsp, tsp);
        const float z  = sigm(dn + noise[n]);
        if (l == 0) {
            out0[n] = x * wsub;
            out1[n] = z;
            out2[n] = dn;
            out3[n] = dn;
            zr[t & 127] = z;
        }
    }
}

// ---------------------------------------------------------------------------
extern "C" void kernel_launch(void* const* d_in, const int* in_sizes, int n_in,
                              void* d_out, int out_size, void* d_ws, size_t ws_size,
                              hipStream_t stream) {
    const float* S_conv  = (const float*)d_in[0];
    const float* Y_anc   = (const float*)d_in[1];
    const float* Z_anc   = (const float*)d_in[2];
    const float* noise   = (const float*)d_in[3];
    const float* C_den   = (const float*)d_in[4];
    const float* W_sub   = (const float*)d_in[5];
    const float* th_syn  = (const float*)d_in[6];
    const float* K_spk   = (const float*)d_in[7];
    const float* tau_spk = (const float*)d_in[8];
    const float* dl_spk  = (const float*)d_in[9];
    const float* th_spk  = (const float*)d_in[10];
    const float* W_spk   = (const float*)d_in[11];
    const float* tau_h   = (const float*)d_in[12];
    const float* K_h     = (const float*)d_in[13];
    const float* dl_h    = (const float*)d_in[14];

    float* out  = (float*)d_out;
    float* out0 = out;
    float* out1 = out + NELEM;
    float* out2 = out + 2 * NELEM;
    float* out3 = out + 3 * NELEM;

    // workspace: A | F | Ct | anc_kT (104 rows) | hist_k | flag
    float* ws     = (float*)d_ws;
    float* wsA    = ws;
    float* wsF    = ws + NELEM;
    float* Ct     = ws + 2 * NELEM;
    float* anc_kT = Ct + S_NO * S_NO;
    float* hist_k = anc_kT + J_PAD * S_NO;
    int*   flag   = (int*)(hist_k + S_NO * T_HIST);

    k1_prep<<<17, 256, 0, stream>>>(C_den, K_spk, tau_spk, dl_spk, tau_h, K_h, dl_h,
                                    Ct, anc_kT, hist_k, flag);
    // A -> ws only (R computed in-register inside K3)
    k2_gemm<<<T_DATA / 32, 256, 0, stream>>>(Z_anc, Ct, wsA);
    // fused conv + R-GEMM + final map
    k3_fused<<<K3_PHYS, 256, 0, stream>>>(wsA, anc_kT, Y_anc, Ct, S_conv, noise,
                                          W_sub, th_syn, th_spk, W_spk,
                                          flag, out0, out1, out2, out3, wsF);
    // exact sequential path (no-op when hist kernel is all-zero)
    k4_scan<<<S_NO, 64, 0, stream>>>(S_conv, noise, W_sub, th_syn, th_spk, W_spk,
                                     hist_k, flag, wsF, out0, out1, out2, out3);
}

// Round 2
// 166.958 us; speedup vs baseline: 1.2551x; 1.2551x over previous
//
#include <hip/hip_runtime.h>

#define T_DATA 20000
#define S_NO   128
#define T_HIST 100
#define J_PAD  112              // conv taps padded to 14 chunks of 8 (zeros past 99)
#define NELEM  (T_DATA * S_NO)  // 2,560,000

__device__ __forceinline__ float sigm(float v) {
    return 1.0f / (1.0f + __expf(-v));
}

__device__ __forceinline__ void fma4(float4& a, float s, const float4 c) {
    a.x = fmaf(s, c.x, a.x); a.y = fmaf(s, c.y, a.y);
    a.z = fmaf(s, c.z, a.z); a.w = fmaf(s, c.w, a.w);
}

// ---------------------------------------------------------------------------
// K1: prep (17 blocks). blocks 0..15: transpose C -> Ct[k][s]
// block 16: ancestor kernel transposed [j][s] (padded to 112), history
// kernel [s][j], flag = any(K_hist != 0)
// ---------------------------------------------------------------------------
__global__ void __launch_bounds__(256) k1_prep(const float* __restrict__ C,
                        const float* __restrict__ K_spike,
                        const float* __restrict__ tau_spike,
                        const float* __restrict__ delta_spike,
                        const float* __restrict__ tau_hist,
                        const float* __restrict__ K_hist,
                        const float* __restrict__ delta_hist,
                        float* __restrict__ Ct,
                        float* __restrict__ anc_kT,
                        float* __restrict__ hist_k,
                        int* __restrict__ flag) {
    const int tid = threadIdx.x;
    const int b   = blockIdx.x;
    if (b < 16) {
#pragma unroll
        for (int i = 0; i < 4; ++i) {
            const int q = b * 1024 + i * 256 + tid;   // q = s*128 + k
            Ct[(q & 127) * S_NO + (q >> 7)] = C[q];
        }
        return;
    }
    const int s    = tid & 127;
    const int half = tid >> 7;
    {   // ancestor kernel transposed, padded: anc_kT[j*128 + s], j in [0,112)
        float d  = delta_spike[s];
        float i0 = __expf(-tau_spike[0]);
        float i1 = __expf(-tau_spike[1]);
        float i2 = __expf(-tau_spike[2]);
        float k0 = K_spike[s * 3 + 0], k1 = K_spike[s * 3 + 1], k2 = K_spike[s * 3 + 2];
        for (int j = half * 56; j < half * 56 + 56; ++j) {
            float v = 0.0f;
            if (j < T_HIST) {
                float t  = fmaxf((float)j - d, 0.0f);
                float x0 = t * i0, x1 = t * i1, x2 = t * i2;
                v = k0 * x0 * __expf(-x0) + k1 * x1 * __expf(-x1) + k2 * x2 * __expf(-x2);
            }
            anc_kT[j * S_NO + s] = v;
        }
    }
    {   // history kernel per-subunit: hist_k[s*100 + j]
        float d  = delta_hist[s];
        float i0 = __expf(-tau_hist[0]);
        float i1 = __expf(-tau_hist[1]);
        float i2 = __expf(-tau_hist[2]);
        float k0 = K_hist[s * 3 + 0], k1 = K_hist[s * 3 + 1], k2 = K_hist[s * 3 + 2];
        for (int j = half * 50; j < half * 50 + 50; ++j) {
            float t  = fmaxf((float)j - d, 0.0f);
            float x0 = t * i0, x1 = t * i1, x2 = t * i2;
            hist_k[s * T_HIST + j] =
                k0 * x0 * __expf(-x0) + k1 * x1 * __expf(-x1) + k2 * x2 * __expf(-x2);
        }
    }
    if (tid == 0) *flag = 0;
    __syncthreads();
    if (tid < 128) {
        if (K_hist[s * 3] != 0.0f || K_hist[s * 3 + 1] != 0.0f || K_hist[s * 3 + 2] != 0.0f)
            atomicOr(flag, 1);
    }
}

// ---------------------------------------------------------------------------
// K2: dual GEMM  A = Z @ C^T (-> ws), R = Y @ C^T (-> out1)
// Known-good round-0 version: block 32t x 128s, thread 4t x 4s.
// ---------------------------------------------------------------------------
__global__ void __launch_bounds__(256) k2_gemm(const float* __restrict__ Z,
                                               const float* __restrict__ Y,
                                               const float* __restrict__ Ct,
                                               float* __restrict__ A,
                                               float* __restrict__ R) {
    __shared__ float Zt[32 * 128];
    __shared__ float Yt[32 * 128];
    const int t0  = blockIdx.x * 32;
    const int tid = threadIdx.x;
    {
        const float4* Zg = (const float4*)(Z + t0 * S_NO);
        const float4* Yg = (const float4*)(Y + t0 * S_NO);
        float4* Zl = (float4*)Zt;
        float4* Yl = (float4*)Yt;
        for (int q = tid; q < 1024; q += 256) { Zl[q] = Zg[q]; Yl[q] = Yg[q]; }
    }
    __syncthreads();
    const int sg = tid & 31;          // s0 = sg*4
    const int tg = tid >> 5;          // 0..7 -> local t = tg*4 + i
    const int s0 = sg * 4;
    float4 accA[4] = {{0,0,0,0},{0,0,0,0},{0,0,0,0},{0,0,0,0}};
    float4 accR[4] = {{0,0,0,0},{0,0,0,0},{0,0,0,0},{0,0,0,0}};
    for (int k4 = 0; k4 < 32; ++k4) {
        const float4 c0 = *(const float4*)&Ct[(k4 * 4 + 0) * S_NO + s0];
        const float4 c1 = *(const float4*)&Ct[(k4 * 4 + 1) * S_NO + s0];
        const float4 c2 = *(const float4*)&Ct[(k4 * 4 + 2) * S_NO + s0];
        const float4 c3 = *(const float4*)&Ct[(k4 * 4 + 3) * S_NO + s0];
#pragma unroll
        for (int i = 0; i < 4; ++i) {
            const float4 z = *(const float4*)&Zt[(tg * 4 + i) * S_NO + k4 * 4];
            fma4(accA[i], z.x, c0); fma4(accA[i], z.y, c1);
            fma4(accA[i], z.z, c2); fma4(accA[i], z.w, c3);
            const float4 y = *(const float4*)&Yt[(tg * 4 + i) * S_NO + k4 * 4];
            fma4(accR[i], y.x, c0); fma4(accR[i], y.y, c1);
            fma4(accR[i], y.z, c2); fma4(accR[i], y.w, c3);
        }
    }
#pragma unroll
    for (int i = 0; i < 4; ++i) {
        *(float4*)&A[(t0 + tg * 4 + i) * S_NO + s0] = accA[i];
        *(float4*)&R[(t0 + tg * 4 + i) * S_NO + s0] = accR[i];
    }
}

// ---------------------------------------------------------------------------
// K3: fused 112-tap (zero-padded) conv + final map. Gather-from-global.
// NEW vs round 0: the 14-chunk serial conv is split across TWO cooperating
// threads (chunk-halves 0-6 / 7-13) whose partials combine through LDS.
// Same total load volume and FMA count, but per-thread dependent chain
// halves and wave count doubles (1250 blocks x 8 waves = 10000 waves vs
// 5000), fixing the grid-limited occupancy (30% measured) of the
// latency-bound round-0 kernel.
// Block: 512 threads = 128 s x 2 t-halves x 2 chunk-halves.
// ---------------------------------------------------------------------------
#define K3_LOGICAL 1250
#define K3_NPER    157                 // ceil(1250/8)
#define K3_PHYS    (8 * K3_NPER)       // 1256

__device__ __forceinline__ void k3_load_chunk(const float* __restrict__ A,
                                              const float* __restrict__ kT,
                                              int t0, int s, int c,
                                              float w[15], float kj[8]) {
    const int B = t0 - 8 * c - 8;
#pragma unroll
    for (int q = 0; q < 15; ++q) w[q] = A[(B + q) * S_NO + s];
#pragma unroll
    for (int r = 0; r < 8; ++r) kj[r] = kT[(8 * c + r) * S_NO + s];
}

__device__ __forceinline__ void k3_fma_chunk(const float w[15], const float kj[8],
                                             float acc[8]) {
#pragma unroll
    for (int r = 0; r < 8; ++r)
#pragma unroll
        for (int i = 0; i < 8; ++i)
            acc[i] = fmaf(kj[r], w[i + 7 - r], acc[i]);   // row = t0+i-1-(8c+r)
}

// guarded (t0 < 112) fallback: serial over this thread's 7 chunks, u>=0 checks
__device__ __forceinline__ void conv7_guard(const float* __restrict__ A,
                                            const float* __restrict__ kT,
                                            int t0, int s, int cbase, float acc[8]) {
#pragma unroll 1
    for (int cc = 0; cc < 7; ++cc) {
        const int c = cbase + cc;
        const int B = t0 - 8 * c - 8;
        float w[15], kj[8];
#pragma unroll
        for (int q = 0; q < 15; ++q) {
            const int u = B + q;
            w[q] = (u >= 0) ? A[u * S_NO + s] : 0.0f;
        }
#pragma unroll
        for (int r = 0; r < 8; ++r) kj[r] = kT[(8 * c + r) * S_NO + s];
        k3_fma_chunk(w, kj, acc);
    }
}

__global__ void __launch_bounds__(512, 4) k3_fused(const float* __restrict__ A,
                                                const float* __restrict__ anc_kT,
                                                const float* __restrict__ S_conv,
                                                const float* __restrict__ noise,
                                                const float* __restrict__ W_sub,
                                                const float* __restrict__ theta_syn,
                                                const float* __restrict__ theta_spike,
                                                const float* __restrict__ W_spike,
                                                const int* __restrict__ flag,
                                                float* __restrict__ out0,
                                                float* __restrict__ out1,
                                                float* __restrict__ out2,
                                                float* __restrict__ out3,
                                                float* __restrict__ Fws) {
    // bijective XCD swizzle over the padded grid [0, 1256)
    const int blk = (blockIdx.x & 7) * K3_NPER + (blockIdx.x >> 3);
    if (blk >= K3_LOGICAL) return;
    __shared__ float part[8][2][128];                     // [i][th][s] — 8 KB
    const int tid = threadIdx.x;
    const int s   = tid & 127;
    const int g   = tid >> 7;                             // wave-uniform (0..3)
    const int th  = g & 1;                                // t-half
    const int ch  = g >> 1;                               // chunk-half
    const int t0  = blk * 16 + th * 8;
    const int fl  = *flag;

    // ch==0 threads own the final map: prefetch its HBM-cold streams early
    float sc[8], nz[8], rr[8];
    if (ch == 0) {
#pragma unroll
        for (int i = 0; i < 8; ++i) {
            const int n = (t0 + i) * S_NO + s;
            sc[i] = S_conv[n];
            nz[i] = noise[n];
            rr[i] = out1[n];          // R = Y @ C^T, written by K2
        }
    }

    float acc[8] = {0,0,0,0,0,0,0,0};
    const int cbase = ch * 7;          // ch0: chunks 0..6, ch1: 7..13
    if (t0 >= J_PAD) {
        // software-pipelined: double-buffered window/taps, rolled x2 loop
        float w0[15], kk0[8], w1[15], kk1[8];
        k3_load_chunk(A, anc_kT, t0, s, cbase, w0, kk0);
#pragma unroll 1
        for (int c = 0; c < 6; c += 2) {
            k3_load_chunk(A, anc_kT, t0, s, cbase + c + 1, w1, kk1);
            k3_fma_chunk(w0, kk0, acc);
            k3_load_chunk(A, anc_kT, t0, s, cbase + c + 2, w0, kk0);
            k3_fma_chunk(w1, kk1, acc);
        }
        k3_fma_chunk(w0, kk0, acc);                       // chunk cbase+6
    } else {
        conv7_guard(A, anc_kT, t0, s, cbase, acc);
    }

    // combine chunk-half partials through LDS
    if (ch == 1) {
#pragma unroll
        for (int i = 0; i < 8; ++i) part[i][th][s] = acc[i];
    }
    __syncthreads();
    if (ch == 1) return;
#pragma unroll
    for (int i = 0; i < 8; ++i) acc[i] += part[i][th][s];

    if (fl == 0) {
        const float tsy = theta_syn[s], wsub = W_sub[s];
        const float wsp = W_spike[s],  tsp  = theta_spike[s];
#pragma unroll
        for (int i = 0; i < 8; ++i) {
            const int n = (t0 + i) * S_NO + s;
            const float x  = sigm(sc[i] + tsy + rr[i] + acc[i]);
            const float dn = fmaf(x, wsp, tsp);
            const float z  = sigm(dn + nz[i]);
            out0[n] = x * wsub;
            out1[n] = z;
            out2[n] = dn;
            out3[n] = dn;
        }
    } else {
#pragma unroll
        for (int i = 0; i < 8; ++i) Fws[(t0 + i) * S_NO + s] = acc[i];
    }
}

// ---------------------------------------------------------------------------
// K4: exact sequential recurrence (only when hist kernel != 0).
// ---------------------------------------------------------------------------
__global__ void __launch_bounds__(64) k4_scan(const float* __restrict__ S_conv,
                                              const float* __restrict__ noise,
                                              const float* __restrict__ W_sub,
                                              const float* __restrict__ theta_syn,
                                              const float* __restrict__ theta_spike,
                                              const float* __restrict__ W_spike,
                                              const float* __restrict__ hist_k,
                                              const int* __restrict__ flag,
                                              const float* __restrict__ Fws,
                                              float* __restrict__ out0,
                                              float* __restrict__ out1,
                                              float* __restrict__ out2,
                                              float* __restrict__ out3) {
    if (*flag == 0) return;
    __shared__ float zr[128];
    const int s = blockIdx.x;
    const int l = threadIdx.x;
    zr[l] = 0.0f; zr[l + 64] = 0.0f;      // single wave: no barrier needed
    const float hk0 = (l < T_HIST) ? hist_k[s * T_HIST + l] : 0.0f;
    const float hk1 = (l + 64 < T_HIST) ? hist_k[s * T_HIST + l + 64] : 0.0f;
    const float tsy = theta_syn[s], wsub = W_sub[s];
    const float wsp = W_spike[s],  tsp  = theta_spike[s];
    for (int t = 0; t < T_DATA; ++t) {
        float fh = hk0 * zr[(t - 1 - l) & 127];
        fh = fmaf(hk1, zr[(t - 65 - l) & 127], fh);
#pragma unroll
        for (int m = 1; m < 64; m <<= 1) fh += __shfl_xor(fh, m, 64);
        const int n = t * S_NO + s;
        const float basev = S_conv[n] + tsy + out1[n] + Fws[n];
        const float x  = sigm(basev + fh);
        const float dn = fmaf(x, wsp, tsp);
        const float z  = sigm(dn + noise[n]);
        if (l == 0) {
            out0[n] = x * wsub;
            out1[n] = z;
            out2[n] = dn;
            out3[n] = dn;
            zr[t & 127] = z;
        }
    }
}

// ---------------------------------------------------------------------------
extern "C" void kernel_launch(void* const* d_in, const int* in_sizes, int n_in,
                              void* d_out, int out_size, void* d_ws, size_t ws_size,
                              hipStream_t stream) {
    const float* S_conv  = (const float*)d_in[0];
    const float* Y_anc   = (const float*)d_in[1];
    const float* Z_anc   = (const float*)d_in[2];
    const float* noise   = (const float*)d_in[3];
    const float* C_den   = (const float*)d_in[4];
    const float* W_sub   = (const float*)d_in[5];
    const float* th_syn  = (const float*)d_in[6];
    const float* K_spk   = (const float*)d_in[7];
    const float* tau_spk = (const float*)d_in[8];
    const float* dl_spk  = (const float*)d_in[9];
    const float* th_spk  = (const float*)d_in[10];
    const float* W_spk   = (const float*)d_in[11];
    const float* tau_h   = (const float*)d_in[12];
    const float* K_h     = (const float*)d_in[13];
    const float* dl_h    = (const float*)d_in[14];

    float* out  = (float*)d_out;
    float* out0 = out;
    float* out1 = out + NELEM;
    float* out2 = out + 2 * NELEM;
    float* out3 = out + 3 * NELEM;

    // workspace: A | F | Ct | anc_kT (112 rows) | hist_k | flag
    float* ws     = (float*)d_ws;
    float* wsA    = ws;
    float* wsF    = ws + NELEM;
    float* Ct     = ws + 2 * NELEM;
    float* anc_kT = Ct + S_NO * S_NO;
    float* hist_k = anc_kT + J_PAD * S_NO;
    int*   flag   = (int*)(hist_k + S_NO * T_HIST);

    k1_prep<<<17, 256, 0, stream>>>(C_den, K_spk, tau_spk, dl_spk, tau_h, K_h, dl_h,
                                    Ct, anc_kT, hist_k, flag);
    // A -> ws, R -> out1
    k2_gemm<<<T_DATA / 32, 256, 0, stream>>>(Z_anc, Y_anc, Ct, wsA, out1);
    // fused conv + final map (reads A from ws, R from out1)
    k3_fused<<<K3_PHYS, 512, 0, stream>>>(wsA, anc_kT, S_conv, noise,
                                          W_sub, th_syn, th_spk, W_spk,
                                          flag, out0, out1, out2, out3, wsF);
    // exact sequential path (no-op when hist kernel is all-zero)
    k4_scan<<<S_NO, 64, 0, stream>>>(S_conv, noise, W_sub, th_syn, th_spk, W_spk,
                                     hist_k, flag, wsF, out0, out1, out2, out3);
}